// Round 1
// baseline (2102.605 us; speedup 1.0000x reference)
//
#include <hip/hip_runtime.h>
#include <hip/hip_bf16.h>

// ---------------------------------------------------------------------------
// Fused 2-layer GRU + ReLU + Linear, one batch element per workgroup (256 CUs).
// Weights live in per-thread VGPRs as packed fp16 (half2), hidden state in LDS
// (fp32 master copy + packed fp16 copy for v_dot2_f32_f16 broadcast reads).
// 768 threads = 12 waves: threads 0..383 own layer-0 gate rows, threads
// 384..767 own layer-1 hidden-gate rows; all threads share W_ih1 half-rows.
// ---------------------------------------------------------------------------

typedef _Float16 h2 __attribute__((ext_vector_type(2)));

#if __has_builtin(__builtin_amdgcn_fdot2)
__device__ __forceinline__ float dot2f(h2 a, h2 b, float c) {
  return __builtin_amdgcn_fdot2(a, b, c, false);
}
#else
__device__ __forceinline__ float dot2f(h2 a, h2 b, float c) {
  return c + (float)a[0] * (float)b[0] + (float)a[1] * (float)b[1];
}
#endif

__device__ __forceinline__ h2 pack2(float x, float y) {
  h2 r; r[0] = (_Float16)x; r[1] = (_Float16)y; return r;
}
__device__ __forceinline__ float sigm(float x) {
  return 1.0f / (1.0f + __expf(-x));
}
__device__ __forceinline__ float tanh_f(float x) {
  x = fminf(fmaxf(x, -15.f), 15.f);
  float e = __expf(2.f * x);
  return (e - 1.f) / (e + 1.f);
}

#define SEQ 1200
#define HID 128
#define INSZ 32

// 4 packed dot2s against one float4 (= 4 half2) of broadcast state
#define DOT4(BASE, Q, ACC)                                             \
  ACC = dot2f(wbig[(BASE) + 0], __builtin_bit_cast(h2, (Q).x), ACC);   \
  ACC = dot2f(wbig[(BASE) + 1], __builtin_bit_cast(h2, (Q).y), ACC);   \
  ACC = dot2f(wbig[(BASE) + 2], __builtin_bit_cast(h2, (Q).z), ACC);   \
  ACC = dot2f(wbig[(BASE) + 3], __builtin_bit_cast(h2, (Q).w), ACC);

__global__ __launch_bounds__(768, 3) void gru_fused(
    const float* __restrict__ x,
    const float* __restrict__ Wih0, const float* __restrict__ Whh0,
    const float* __restrict__ bih0, const float* __restrict__ bhh0,
    const float* __restrict__ Wih1, const float* __restrict__ Whh1,
    const float* __restrict__ bih1, const float* __restrict__ bhh1,
    const float* __restrict__ Wlin, const float* __restrict__ blin,
    float* __restrict__ out)
{
  const int tid = threadIdx.x;
  const int b   = blockIdx.x;
  const int wrow = tid >> 1;   // W_ih1 row this thread helps with
  const int rsel = tid & 1;    // which k-half of that row

  // pre-activation staging
  __shared__ float aX[384];    // layer0: x-part + b_ih0
  __shared__ float aH[384];    // layer0: h-part + b_hh0
  __shared__ float aX1[384];   // layer1: input-part (W_ih1 h1) + b_ih1
  __shared__ float bH1[384];   // layer1: hidden-part + b_hh1
  // hidden states
  __shared__ float  s0f[HID], s1f[HID];      // fp32 master
  __shared__ float4 s0h4[16], s1h4[16];      // packed fp16 copies (128 halfs)
  __shared__ float4 xh4[2][4];               // packed fp16 x_t double buffer
  __shared__ float  red[2];

  // ---- per-thread weight registers (packed fp16) ----
  // layout (all compile-time indices):
  //   [0..31]   : W_ih1[wrow, rsel*64 .. +64)          (all threads)
  //   t<384     : [32..47] W_ih0 row t ; [48..111] W_hh0 row t
  //   t>=384    : [32..95] W_hh1 row (t-384)
  h2 wbig[112];

  {
    const float2* p = (const float2*)Wih1 + (size_t)wrow * 64 + rsel * 32;
#pragma unroll
    for (int i = 0; i < 32; ++i) { float2 v = p[i]; wbig[i] = pack2(v.x, v.y); }
  }
  float bi0 = 0.f, bh0 = 0.f, bh1v = 0.f;
  const float bi1 = bih1[wrow];
  if (tid < 384) {
    const float2* pi = (const float2*)Wih0 + (size_t)tid * 16;
#pragma unroll
    for (int i = 0; i < 16; ++i) { float2 v = pi[i]; wbig[32 + i] = pack2(v.x, v.y); }
    const float2* ph = (const float2*)Whh0 + (size_t)tid * 64;
#pragma unroll
    for (int i = 0; i < 64; ++i) { float2 v = ph[i]; wbig[48 + i] = pack2(v.x, v.y); }
    bi0 = bih0[tid]; bh0 = bhh0[tid];
  } else {
    const int o = tid - 384;
    const float2* ph = (const float2*)Whh1 + (size_t)o * 64;
#pragma unroll
    for (int i = 0; i < 64; ++i) { float2 v = ph[i]; wbig[32 + i] = pack2(v.x, v.y); }
    bh1v = bhh1[o];
  }
  const float wl = (tid < HID) ? Wlin[tid] : 0.f;
  const float bl = blin[0];

  // ---- init state + preload x_0 ----
  if (tid < HID) { s0f[tid] = 0.f; s1f[tid] = 0.f; }
  if (tid < 16) {
    s0h4[tid] = float4{0.f, 0.f, 0.f, 0.f};
    s1h4[tid] = float4{0.f, 0.f, 0.f, 0.f};
    float2 v = ((const float2*)x)[(size_t)b * SEQ * 16 + tid];
    ((h2*)xh4)[tid] = pack2(v.x, v.y);
  }
  __syncthreads();

  float* outp = out + (size_t)b * SEQ;
  const float2* xsrc = (const float2*)x + (size_t)b * SEQ * 16;

  for (int st = 0; st < SEQ; ++st) {
    // ---------------- P1: big row dots ----------------
    if (tid < 384) {
      float ax = bi0, ah = bh0;
      const float4* xb = xh4[st & 1];
#pragma unroll
      for (int m = 0; m < 4; ++m) { float4 q = xb[m]; DOT4(32 + 4 * m, q, ax) }
#pragma unroll
      for (int m = 0; m < 16; ++m) { float4 q = s0h4[m]; DOT4(48 + 4 * m, q, ah) }
      aX[tid] = ax; aH[tid] = ah;
    } else {
      float a = bh1v;
#pragma unroll
      for (int m = 0; m < 16; ++m) { float4 q = s1h4[m]; DOT4(32 + 4 * m, q, a) }
      bH1[tid - 384] = a;
    }
    // prefetch next timestep's x row (lands in P3)
    float2 xnext;
    const bool pf = (tid < 16) && (st + 1 < SEQ);
    if (pf) xnext = xsrc[(size_t)(st + 1) * 16 + tid];
    __syncthreads();

    // ---------------- P2: layer-0 elementwise update ----------------
    if (tid < HID) {
      float r = sigm(aX[tid] + aH[tid]);
      float z = sigm(aX[HID + tid] + aH[HID + tid]);
      float n = tanh_f(aX[2 * HID + tid] + r * aH[2 * HID + tid]);
      float h = (1.f - z) * n + z * s0f[tid];
      s0f[tid] = h;
      ((_Float16*)s0h4)[tid] = (_Float16)h;
    }
    __syncthreads();

    // ---------------- P3: W_ih1 * h1_t (k-split x2) ----------------
    {
      float a = 0.f;
      const float4* sb = s0h4 + rsel * 8;
#pragma unroll
      for (int m = 0; m < 8; ++m) { float4 q = sb[m]; DOT4(4 * m, q, a) }
      a += __shfl_xor(a, 1, 64);
      if (rsel == 0) aX1[wrow] = a + bi1;
      if (pf) ((h2*)&xh4[(st + 1) & 1][0])[tid] = pack2(xnext.x, xnext.y);
    }
    __syncthreads();

    // ---------------- P4: layer-1 update + output dot ----------------
    if (tid < HID) {
      float r = sigm(aX1[tid] + bH1[tid]);
      float z = sigm(aX1[HID + tid] + bH1[HID + tid]);
      float n = tanh_f(aX1[2 * HID + tid] + r * bH1[2 * HID + tid]);
      float h = (1.f - z) * n + z * s1f[tid];
      s1f[tid] = h;
      ((_Float16*)s1h4)[tid] = (_Float16)h;
      float p = fmaxf(h, 0.f) * wl;
#pragma unroll
      for (int off = 32; off; off >>= 1) p += __shfl_xor(p, off, 64);
      if ((tid & 63) == 0) red[tid >> 6] = p;
    }
    __syncthreads();
    if (tid == 0) outp[st] = red[0] + red[1] + bl;
  }
}

extern "C" void kernel_launch(void* const* d_in, const int* in_sizes, int n_in,
                              void* d_out, int out_size, void* d_ws, size_t ws_size,
                              hipStream_t stream) {
  const float* x    = (const float*)d_in[0];
  const float* Wih0 = (const float*)d_in[1];
  const float* Whh0 = (const float*)d_in[2];
  const float* bih0 = (const float*)d_in[3];
  const float* bhh0 = (const float*)d_in[4];
  const float* Wih1 = (const float*)d_in[5];
  const float* Whh1 = (const float*)d_in[6];
  const float* bih1 = (const float*)d_in[7];
  const float* bhh1 = (const float*)d_in[8];
  const float* Wlin = (const float*)d_in[9];
  const float* blin = (const float*)d_in[10];
  float* outp = (float*)d_out;

  const int Bn = in_sizes[0] / (SEQ * INSZ);   // 256
  hipLaunchKernelGGL(gru_fused, dim3(Bn), dim3(768), 0, stream,
                     x, Wih0, Whh0, bih0, bhh0,
                     Wih1, Whh1, bih1, bhh1, Wlin, blin, outp);
}

// Round 2
// 1353.721 us; speedup vs baseline: 1.5532x; 1.5532x over previous
//
#include <hip/hip_runtime.h>
#include <hip/hip_bf16.h>

// ---------------------------------------------------------------------------
// Fused 2-layer GRU + ReLU + Linear. One batch element per workgroup (256 WGs).
// Cross-layer pipelined: per step, phase M computes L2 gate pre-acts for time t
// AND L1 gate pre-acts for time t+1 (both only need h1_t, h2_{t-1}, x_{t+1});
// phase E updates both hidden states in parallel. 2 barriers/step.
// 512 threads = 8 waves (2/SIMD, 256-VGPR cap -> weights stay in arch VGPRs).
// Work split: quad (4 lanes) owns rows {q, 128+q, 256+q} of both layers,
// k-split x4 across the quad; partials summed by the E-phase reader via LDS.
// ---------------------------------------------------------------------------

typedef _Float16 h2 __attribute__((ext_vector_type(2)));

#if __has_builtin(__builtin_amdgcn_fdot2)
__device__ __forceinline__ float dot2f(h2 a, h2 b, float c) {
  return __builtin_amdgcn_fdot2(a, b, c, false);
}
#else
__device__ __forceinline__ float dot2f(h2 a, h2 b, float c) {
  return c + (float)a[0] * (float)b[0] + (float)a[1] * (float)b[1];
}
#endif

__device__ __forceinline__ h2 pack2(float x, float y) {
  h2 r; r[0] = (_Float16)x; r[1] = (_Float16)y; return r;
}
__device__ __forceinline__ float sigm(float x) {
  return 1.0f / (1.0f + __expf(-x));
}
__device__ __forceinline__ float tanh_f(float x) {
  x = fminf(fmaxf(x, -15.f), 15.f);
  float e = __expf(2.f * x);
  return (e - 1.f) / (e + 1.f);
}
__device__ __forceinline__ float hsum(float4 v) { return (v.x + v.y) + (v.z + v.w); }

__device__ __forceinline__ void load_pack8(const float* p, h2* w) {
  float4 a = ((const float4*)p)[0], b = ((const float4*)p)[1];
  w[0] = pack2(a.x, a.y); w[1] = pack2(a.z, a.w);
  w[2] = pack2(b.x, b.y); w[3] = pack2(b.z, b.w);
}

#define SEQ 1200
#define HID 128
#define INSZ 32

#define DOT4Q(W, F, ACC)                                                \
  ACC = dot2f((W)[0], __builtin_bit_cast(h2, (F).x), ACC);              \
  ACC = dot2f((W)[1], __builtin_bit_cast(h2, (F).y), ACC);              \
  ACC = dot2f((W)[2], __builtin_bit_cast(h2, (F).z), ACC);              \
  ACC = dot2f((W)[3], __builtin_bit_cast(h2, (F).w), ACC);

#define DOT16Q(W, FA, FB, FC, FD, ACC)                                  \
  DOT4Q(&(W)[0],  FA, ACC) DOT4Q(&(W)[4],  FB, ACC)                     \
  DOT4Q(&(W)[8],  FC, ACC) DOT4Q(&(W)[12], FD, ACC)

__global__ __launch_bounds__(512, 2) void gru_fused(
    const float* __restrict__ x,
    const float* __restrict__ Wih0, const float* __restrict__ Whh0,
    const float* __restrict__ bih0, const float* __restrict__ bhh0,
    const float* __restrict__ Wih1, const float* __restrict__ Whh1,
    const float* __restrict__ bih1, const float* __restrict__ bhh1,
    const float* __restrict__ Wlin, const float* __restrict__ blin,
    float* __restrict__ out)
{
  const int tid = threadIdx.x;
  const int b   = blockIdx.x;
  const int q   = tid >> 2;   // quad id 0..127 -> rows {q, 128+q, 256+q}
  const int ql  = tid & 3;    // k-quarter within the row

  // gate pre-activation partials: [slot(4)][quad(128)][lane(4)] f32
  __shared__ float G1p[4 * 512];   // layer1 (r, z, nx, nh)
  __shared__ float G2p[4 * 512];   // layer2
  __shared__ float  s0f[HID], s1f[HID];        // fp32 master states
  __shared__ float4 s0h4[16], s1h4[16];        // packed fp16 states (128 halfs)
  __shared__ float4 xh[2][4];                  // packed fp16 x row, double buffer
  __shared__ float  pbf[32];                   // output partials, double buffer

  // ---- per-thread weight registers (packed fp16), all compile-time indexed ----
  h2 wi0[3][4];    // W_ih0 rows {q,128+q,256+q}, quarter ql (8 elems each)
  h2 wh0[3][16];   // W_hh0 rows, quarter ql (32 elems each)
  h2 wi1[3][16];   // W_ih1 rows
  h2 wh1[3][16];   // W_hh1 rows
#pragma unroll
  for (int rr = 0; rr < 3; ++rr) {
    const int row = rr * HID + q;
    load_pack8(Wih0 + (size_t)row * INSZ + ql * 8, wi0[rr]);
#pragma unroll
    for (int c = 0; c < 4; ++c) {
      load_pack8(Whh0 + (size_t)row * HID + ql * 32 + c * 8, &wh0[rr][c * 4]);
      load_pack8(Wih1 + (size_t)row * HID + ql * 32 + c * 8, &wi1[rr][c * 4]);
      load_pack8(Whh1 + (size_t)row * HID + ql * 32 + c * 8, &wh1[rr][c * 4]);
    }
  }

  // E-phase per-thread constants
  float bA = 0.f, bB = 0.f, bC = 0.f, bD = 0.f, wl = 0.f;
  if (tid < 128) {                 // L2 updater for row-group tid
    bA = bih1[tid] + bhh1[tid];
    bB = bih1[HID + tid] + bhh1[HID + tid];
    bC = bih1[2 * HID + tid];
    bD = bhh1[2 * HID + tid];
    wl = Wlin[tid];
  } else if (tid < 256) {          // L1 updater
    const int i = tid - 128;
    bA = bih0[i] + bhh0[i];
    bB = bih0[HID + i] + bhh0[HID + i];
    bC = bih0[2 * HID + i];
    bD = bhh0[2 * HID + i];
  }
  const float blv = blin[0];

  // ---- init: zero states, pack x_0 into xh[0] ----
  if (tid < HID) { s0f[tid] = 0.f; s1f[tid] = 0.f; }
  if (tid < 64) { ((float*)s0h4)[tid] = 0.f; ((float*)s1h4)[tid] = 0.f; }
  const float2* xsrc = (const float2*)x + (size_t)b * SEQ * (INSZ / 2);
  if (tid < 16) {
    float2 v = xsrc[tid];
    ((h2*)xh[0])[tid] = pack2(v.x, v.y);
  }
  __syncthreads();

  float* outp = out + (size_t)b * SEQ;

  for (int t = -1; t < SEQ; ++t) {
    // ================= phase M: all matvec partials =================
    {
      const int buf = (t + 1) & 1;
      const float4 xq = xh[buf][ql];
      const float4 sA = s0h4[ql * 4 + 0], sB = s0h4[ql * 4 + 1],
                   sC = s0h4[ql * 4 + 2], sD = s0h4[ql * 4 + 3];
      const float4 tA = s1h4[ql * 4 + 0], tB = s1h4[ql * 4 + 1],
                   tC = s1h4[ql * 4 + 2], tD = s1h4[ql * 4 + 3];
      float a0 = 0.f, a1 = 0.f, a2 = 0.f, a3 = 0.f;
      DOT4Q(wi0[0], xq, a0) DOT16Q(wh0[0], sA, sB, sC, sD, a0)   // L1 r (merged)
      DOT4Q(wi0[1], xq, a1) DOT16Q(wh0[1], sA, sB, sC, sD, a1)   // L1 z (merged)
      DOT4Q(wi0[2], xq, a2)                                      // L1 n, x-part
      DOT16Q(wh0[2], sA, sB, sC, sD, a3)                         // L1 n, h-part
      float c0 = 0.f, c1 = 0.f, c2 = 0.f, c3 = 0.f;
      DOT16Q(wi1[0], sA, sB, sC, sD, c0) DOT16Q(wh1[0], tA, tB, tC, tD, c0)
      DOT16Q(wi1[1], sA, sB, sC, sD, c1) DOT16Q(wh1[1], tA, tB, tC, tD, c1)
      DOT16Q(wi1[2], sA, sB, sC, sD, c2)
      DOT16Q(wh1[2], tA, tB, tC, tD, c3)
      G1p[tid] = a0; G1p[512 + tid] = a1; G1p[1024 + tid] = a2; G1p[1536 + tid] = a3;
      G2p[tid] = c0; G2p[512 + tid] = c1; G2p[1024 + tid] = c2; G2p[1536 + tid] = c3;
    }
    // x_{t+2} prefetch (issued here, packed in E by the same threads)
    float2 xn;
    if ((tid & ~15) == 256) {
      const int ti = (t + 2 < SEQ) ? t + 2 : SEQ - 1;
      xn = xsrc[(size_t)ti * 16 + (tid - 256)];
    }
    __syncthreads();

    // ================= phase E: state updates =================
    if (tid < 128) {
      if (t >= 0) {  // layer-2 update -> h2_t, output partials
        const float4* G4 = (const float4*)G2p;
        float4 r4 = G4[tid], z4 = G4[128 + tid], x4 = G4[256 + tid], h4 = G4[384 + tid];
        float r = sigm(hsum(r4) + bA);
        float z = sigm(hsum(z4) + bB);
        float n = tanh_f(hsum(x4) + bC + r * (hsum(h4) + bD));
        float h = (1.f - z) * n + z * s1f[tid];
        s1f[tid] = h;
        ((_Float16*)s1h4)[tid] = (_Float16)h;
        float p = fmaxf(h, 0.f) * wl;
        p += __shfl_xor(p, 1, 64);
        p += __shfl_xor(p, 2, 64);
        p += __shfl_xor(p, 4, 64);
        if ((tid & 7) == 0) pbf[(t & 1) * 16 + (tid >> 3)] = p;
      }
    } else if (tid < 256) {  // layer-1 update -> h1_{t+1}
      const int i = tid - 128;
      const float4* G4 = (const float4*)G1p;
      float4 r4 = G4[i], z4 = G4[128 + i], x4 = G4[256 + i], h4 = G4[384 + i];
      float r = sigm(hsum(r4) + bA);
      float z = sigm(hsum(z4) + bB);
      float n = tanh_f(hsum(x4) + bC + r * (hsum(h4) + bD));
      float h = (1.f - z) * n + z * s0f[i];
      s0f[i] = h;
      ((_Float16*)s0h4)[i] = (_Float16)h;
    } else if (tid < 272) {  // pack x_{t+2}
      ((h2*)xh[t & 1])[tid - 256] = pack2(xn.x, xn.y);
    } else if (tid == 320 && t >= 1) {  // store out[t-1] from previous partials
      const float4* p4 = (const float4*)(pbf + ((t - 1) & 1) * 16);
      outp[t - 1] = hsum(p4[0]) + hsum(p4[1]) + hsum(p4[2]) + hsum(p4[3]) + blv;
    }
    __syncthreads();
  }

  if (tid == 0) {
    const float4* p4 = (const float4*)(pbf + ((SEQ - 1) & 1) * 16);
    outp[SEQ - 1] = hsum(p4[0]) + hsum(p4[1]) + hsum(p4[2]) + hsum(p4[3]) + blv;
  }
}

extern "C" void kernel_launch(void* const* d_in, const int* in_sizes, int n_in,
                              void* d_out, int out_size, void* d_ws, size_t ws_size,
                              hipStream_t stream) {
  const float* x    = (const float*)d_in[0];
  const float* Wih0 = (const float*)d_in[1];
  const float* Whh0 = (const float*)d_in[2];
  const float* bih0 = (const float*)d_in[3];
  const float* bhh0 = (const float*)d_in[4];
  const float* Wih1 = (const float*)d_in[5];
  const float* Whh1 = (const float*)d_in[6];
  const float* bih1 = (const float*)d_in[7];
  const float* bhh1 = (const float*)d_in[8];
  const float* Wlin = (const float*)d_in[9];
  const float* blin = (const float*)d_in[10];
  float* outp = (float*)d_out;

  const int Bn = in_sizes[0] / (SEQ * INSZ);   // 256
  hipLaunchKernelGGL(gru_fused, dim3(Bn), dim3(512), 0, stream,
                     x, Wih0, Whh0, bih0, bhh0,
                     Wih1, Whh1, bih1, bhh1, Wlin, blin, outp);
}